// Round 1
// baseline (183.297 us; speedup 1.0000x reference)
//
#include <hip/hip_runtime.h>
#include <stdint.h>

#define NSTATES 12870   // C(16,8)
#define NPAIRS  3432    // C(14,7)
#define NGATES  240     // 32 layers: 16*8 + 16*7
#define PERIOD  15      // gate sequence repeats every 2 layers (8+7 gates)
#define TPB     512
#define NITER   6       // 6*512 = 3072 full, tail = 3432-3072 = 360

// Pack the 15 distinct gate pair-lists into (a | b<<16), and precompute cos/sin.
__global__ __launch_bounds__(256) void prep_kernel(
    const int* __restrict__ pairs, const float* __restrict__ angles,
    uint32_t* __restrict__ packed, float2* __restrict__ cs) {
  int i = blockIdx.x * blockDim.x + threadIdx.x;
  if (i < PERIOD * NPAIRS) {
    uint32_t a = (uint32_t)pairs[2 * i];
    uint32_t b = (uint32_t)pairs[2 * i + 1];
    packed[i] = a | (b << 16);
  }
  if (i < NGATES) {
    float t = angles[i];
    cs[i] = make_float2(cosf(t), sinf(t));
  }
}

// One block per batch row; full state row lives in LDS for all 240 gates.
template <bool PACKED>
__global__ __launch_bounds__(TPB) void rbs_kernel(
    const float* __restrict__ in,
    const uint32_t* __restrict__ packed,  // PACKED path
    const float2* __restrict__ cs,        // PACKED path
    const int* __restrict__ pairs_raw,    // fallback path
    const float* __restrict__ angles,     // fallback path
    float* __restrict__ out) {
  __shared__ float st[NSTATES];
  __shared__ float2 csl[NGATES];
  const int tid = threadIdx.x;
  const size_t row = blockIdx.x;

  const float* __restrict__ src = in + row * NSTATES;
  for (int i = tid; i < NSTATES; i += TPB) st[i] = src[i];
  if (PACKED) {
    for (int i = tid; i < NGATES; i += TPB) csl[i] = cs[i];
  } else {
    for (int i = tid; i < NGATES; i += TPB) {
      float t = angles[i];
      csl[i] = make_float2(cosf(t), sinf(t));
    }
  }
  __syncthreads();

  auto load_pair = [&](int d, int p) -> uint32_t {
    if (PACKED) {
      return packed[d * NPAIRS + p];
    } else {
      int2 ab = ((const int2*)pairs_raw)[d * NPAIRS + p];
      return (uint32_t)ab.x | ((uint32_t)ab.y << 16);
    }
  };

  const int ptail = NITER * TPB + tid;
  const bool hastail = ptail < NPAIRS;

  // Prefetch gate 0's pair data into registers.
  uint32_t ucur[NITER + 1];
#pragma unroll
  for (int k = 0; k < NITER; ++k) ucur[k] = load_pair(0, k * TPB + tid);
  if (hastail) ucur[NITER] = load_pair(0, ptail);

  int d = 0;
  for (int g = 0; g < NGATES; ++g) {
    const int dn = (d + 1 == PERIOD) ? 0 : d + 1;

    // Prefetch next gate's pair data (hides L2 latency under LDS work).
    uint32_t unxt[NITER + 1];
    if (g + 1 < NGATES) {
#pragma unroll
      for (int k = 0; k < NITER; ++k) unxt[k] = load_pair(dn, k * TPB + tid);
      if (hastail) unxt[NITER] = load_pair(dn, ptail);
    }

    const float c = csl[g].x;
    const float s = csl[g].y;

    // All reads first (ILP on the LDS pipe), then all writes.
    // Pairs within a gate are disjoint -> no intra-gate hazards.
    uint32_t aa[NITER + 1], bb[NITER + 1];
    float xi[NITER + 1], xj[NITER + 1];
#pragma unroll
    for (int k = 0; k < NITER; ++k) {
      aa[k] = ucur[k] & 0xFFFFu;
      bb[k] = ucur[k] >> 16;
      xi[k] = st[aa[k]];
      xj[k] = st[bb[k]];
    }
    if (hastail) {
      aa[NITER] = ucur[NITER] & 0xFFFFu;
      bb[NITER] = ucur[NITER] >> 16;
      xi[NITER] = st[aa[NITER]];
      xj[NITER] = st[bb[NITER]];
    }
#pragma unroll
    for (int k = 0; k < NITER; ++k) {
      st[aa[k]] = fmaf(c, xi[k], s * xj[k]);
      st[bb[k]] = fmaf(c, xj[k], -s * xi[k]);
    }
    if (hastail) {
      st[aa[NITER]] = fmaf(c, xi[NITER], s * xj[NITER]);
      st[bb[NITER]] = fmaf(c, xj[NITER], -s * xi[NITER]);
    }

    __syncthreads();
    d = dn;
#pragma unroll
    for (int k = 0; k <= NITER; ++k) ucur[k] = unxt[k];
  }

  float* __restrict__ dst = out + row * NSTATES;
  for (int i = tid; i < NSTATES; i += TPB) dst[i] = st[i];
}

extern "C" void kernel_launch(void* const* d_in, const int* in_sizes, int n_in,
                              void* d_out, int out_size, void* d_ws, size_t ws_size,
                              hipStream_t stream) {
  const float* in = (const float*)d_in[0];
  const float* angles = (const float*)d_in[1];
  const int* pairs = (const int*)d_in[2];
  float* out = (float*)d_out;

  const size_t packed_bytes = (size_t)PERIOD * NPAIRS * sizeof(uint32_t); // 205920
  const size_t need = packed_bytes + (size_t)NGATES * sizeof(float2);

  if (d_ws != nullptr && ws_size >= need) {
    uint32_t* packed = (uint32_t*)d_ws;
    float2* cs = (float2*)((char*)d_ws + packed_bytes); // offset 205920, 8B-aligned
    const int total = PERIOD * NPAIRS; // 51480
    const int nb = (total + 255) / 256;
    prep_kernel<<<nb, 256, 0, stream>>>(pairs, angles, packed, cs);
    rbs_kernel<true><<<256, TPB, 0, stream>>>(in, packed, cs, nullptr, nullptr, out);
  } else {
    // Fallback: read raw int32 pairs (rows repeat with period 15), compute
    // cos/sin per block. Slower but needs no workspace.
    rbs_kernel<false><<<256, TPB, 0, stream>>>(in, nullptr, nullptr, pairs, angles, out);
  }
}

// Round 2
// 156.962 us; speedup vs baseline: 1.1678x; 1.1678x over previous
//
#include <hip/hip_runtime.h>
#include <stdint.h>

#define NSTATES 12870   // C(16,8)
#define NPAIRS  3432    // C(14,7)
#define NGATES  240     // 32 layers: 16*8 + 16*7
#define PERIOD  15      // gate sequence repeats every 2 layers (8+7 gates)
#define TPB     1024
#define NITER   3       // 3*1024 = 3072 full, tail = 3432-3072 = 360

// Pack the 15 distinct gate pair-lists into (a | b<<16), and precompute cos/sin.
__global__ __launch_bounds__(256) void prep_kernel(
    const int* __restrict__ pairs, const float* __restrict__ angles,
    uint32_t* __restrict__ packed, float2* __restrict__ cs) {
  int i = blockIdx.x * blockDim.x + threadIdx.x;
  if (i < PERIOD * NPAIRS) {
    uint32_t a = (uint32_t)pairs[2 * i];
    uint32_t b = (uint32_t)pairs[2 * i + 1];
    packed[i] = a | (b << 16);
  }
  if (i < NGATES) {
    float t = angles[i];
    cs[i] = make_float2(cosf(t), sinf(t));
  }
}

// One block per batch row; full state row lives in LDS for all 240 gates.
template <bool PACKED>
__global__ __launch_bounds__(TPB) void rbs_kernel(
    const float* __restrict__ in,
    const uint32_t* __restrict__ packed,  // PACKED path
    const float2* __restrict__ cs,        // PACKED path
    const int* __restrict__ pairs_raw,    // fallback path
    const float* __restrict__ angles,     // fallback path
    float* __restrict__ out) {
  __shared__ float st[NSTATES];
  __shared__ float2 csl[NGATES];
  const int tid = threadIdx.x;
  const size_t row = blockIdx.x;

  const float* __restrict__ src = in + row * NSTATES;
  for (int i = tid; i < NSTATES; i += TPB) st[i] = src[i];
  if (PACKED) {
    for (int i = tid; i < NGATES; i += TPB) csl[i] = cs[i];
  } else {
    for (int i = tid; i < NGATES; i += TPB) {
      float t = angles[i];
      csl[i] = make_float2(cosf(t), sinf(t));
    }
  }
  __syncthreads();

  auto load_pair = [&](int d, int p) -> uint32_t {
    if (PACKED) {
      return packed[d * NPAIRS + p];
    } else {
      int2 ab = ((const int2*)pairs_raw)[d * NPAIRS + p];
      return (uint32_t)ab.x | ((uint32_t)ab.y << 16);
    }
  };

  const int ptail = NITER * TPB + tid;
  const bool hastail = ptail < NPAIRS;

  // Prefetch gate 0's pair data into registers.
  uint32_t ucur[NITER + 1];
#pragma unroll
  for (int k = 0; k < NITER; ++k) ucur[k] = load_pair(0, k * TPB + tid);
  if (hastail) ucur[NITER] = load_pair(0, ptail);

  int d = 0;
  for (int g = 0; g < NGATES; ++g) {
    const int dn = (d + 1 == PERIOD) ? 0 : d + 1;

    // Prefetch next gate's pair data (hides L2 latency under LDS work).
    uint32_t unxt[NITER + 1];
    if (g + 1 < NGATES) {
#pragma unroll
      for (int k = 0; k < NITER; ++k) unxt[k] = load_pair(dn, k * TPB + tid);
      if (hastail) unxt[NITER] = load_pair(dn, ptail);
    }

    const float c = csl[g].x;
    const float s = csl[g].y;

    // All reads first (ILP on the LDS pipe), then all writes.
    // Pairs within a gate are disjoint -> no intra-gate hazards.
    uint32_t aa[NITER + 1], bb[NITER + 1];
    float xi[NITER + 1], xj[NITER + 1];
#pragma unroll
    for (int k = 0; k < NITER; ++k) {
      aa[k] = ucur[k] & 0xFFFFu;
      bb[k] = ucur[k] >> 16;
      xi[k] = st[aa[k]];
      xj[k] = st[bb[k]];
    }
    if (hastail) {
      aa[NITER] = ucur[NITER] & 0xFFFFu;
      bb[NITER] = ucur[NITER] >> 16;
      xi[NITER] = st[aa[NITER]];
      xj[NITER] = st[bb[NITER]];
    }
#pragma unroll
    for (int k = 0; k < NITER; ++k) {
      st[aa[k]] = fmaf(c, xi[k], s * xj[k]);
      st[bb[k]] = fmaf(c, xj[k], -s * xi[k]);
    }
    if (hastail) {
      st[aa[NITER]] = fmaf(c, xi[NITER], s * xj[NITER]);
      st[bb[NITER]] = fmaf(c, xj[NITER], -s * xi[NITER]);
    }

    __syncthreads();
    d = dn;
#pragma unroll
    for (int k = 0; k <= NITER; ++k) ucur[k] = unxt[k];
  }

  float* __restrict__ dst = out + row * NSTATES;
  for (int i = tid; i < NSTATES; i += TPB) dst[i] = st[i];
}

extern "C" void kernel_launch(void* const* d_in, const int* in_sizes, int n_in,
                              void* d_out, int out_size, void* d_ws, size_t ws_size,
                              hipStream_t stream) {
  const float* in = (const float*)d_in[0];
  const float* angles = (const float*)d_in[1];
  const int* pairs = (const int*)d_in[2];
  float* out = (float*)d_out;

  const size_t packed_bytes = (size_t)PERIOD * NPAIRS * sizeof(uint32_t); // 205920
  const size_t need = packed_bytes + (size_t)NGATES * sizeof(float2);

  if (d_ws != nullptr && ws_size >= need) {
    uint32_t* packed = (uint32_t*)d_ws;
    float2* cs = (float2*)((char*)d_ws + packed_bytes); // offset 205920, 8B-aligned
    const int total = PERIOD * NPAIRS; // 51480
    const int nb = (total + 255) / 256;
    prep_kernel<<<nb, 256, 0, stream>>>(pairs, angles, packed, cs);
    rbs_kernel<true><<<256, TPB, 0, stream>>>(in, packed, cs, nullptr, nullptr, out);
  } else {
    // Fallback: read raw int32 pairs (rows repeat with period 15), compute
    // cos/sin per block. Slower but needs no workspace.
    rbs_kernel<false><<<256, TPB, 0, stream>>>(in, nullptr, nullptr, pairs, angles, out);
  }
}

// Round 4
// 123.072 us; speedup vs baseline: 1.4893x; 1.2754x over previous
//
#include <hip/hip_runtime.h>
#include <stdint.h>

#define NSTATES 12870   // C(16,8)
#define NPAIRS  3432
#define NGATES  240
#define PERIOD  15
#define NLP     16      // layer-pairs (32 layers)
#define TPB     1024

// ---------------- workspace layout (bytes) ----------------
// [CS_OFF]  float2 cs[240]                  : 1920 B
// [BLK_OFF] 4 blocks x 23760 B:
//            pair-units [792][8]u16 (w1 members 0..3, w3 members 0..3)
//            w2 units   [924][6]u16 at +12672
// [BND_OFF] boundary: m3 [252][8]u16 | m2 3x[420][4]u16 | m1 3x[744][2]u16
#define CS_OFF      0
#define BLK_OFF     1920
#define BLK_BYTES   23760
#define PU_ROWS     792
#define W2_ROWS     924
#define W2_SUB_OFF  12672
#define BND_OFF     96960
#define M2_OFF      4032      // 252*16
#define M1_OFF      14112     // 4032 + 3*420*8
#define WS_NEED     120000

__device__ __constant__ uint8_t OUTPOS[4][12] = {
  {4,5,6,7,8,9,10,11,12,13,14,15},
  {0,1,2,3,8,9,10,11,12,13,14,15},
  {0,1,2,3,4,5,6,7,12,13,14,15},
  {0,1,2,3,4,5,6,7,8,9,10,11}
};
__device__ __constant__ uint8_t FREEPOS[10] = {0,1,2,5,6,9,10,13,14,15};

// ---------------- prep: build all metadata deterministically ----------------
__global__ __launch_bounds__(256) void prep_fused(
    const float* __restrict__ angles, uint8_t* __restrict__ ws) {
  __shared__ int C[17][9];
  if (threadIdx.x == 0) {
    for (int n = 0; n <= 16; ++n)
      for (int k = 0; k <= 8; ++k)
        C[n][k] = (k == 0) ? 1 : ((k > n) ? 0 : C[n-1][k-1] + C[n-1][k]);
  }
  __syncthreads();

  auto rankof = [&](uint32_t mask) -> int {
    int r = C[16][8] - 1, i = 0;
    for (int c = 0; c < 16; ++c)
      if ((mask >> c) & 1) { r -= C[15 - c][8 - i]; ++i; }
    return r;  // lex rank of 8-combination, matches itertools.combinations
  };
  auto unrank_mask = [&](int n, int k, int r, const uint8_t* pos) -> uint32_t {
    uint32_t m = 0; int v = 0;
    for (int i = 0; i < k; ++i) {
      for (;;) { int cnt = C[n - 1 - v][k - 1 - i]; if (r < cnt) break; r -= cnt; ++v; }
      m |= 1u << pos[v]; ++v;
    }
    return m;
  };

  int u = blockIdx.x * 256 + threadIdx.x;
  if (u < 10032) {                       // block-orbit metadata
    int b = u / 2508, r = u % 2508;
    int p0 = 4 * b;
    uint32_t bmask = 0xFu << p0;
    uint8_t* blk = ws + BLK_OFF + b * BLK_BYTES;
    if (r < PU_ROWS) {                   // w=1 orbit r: member m = occ at p0+m
      uint32_t mo = unrank_mask(12, 7, r, OUTPOS[b]);
      uint32_t m0 = rankof(mo | (1u << (p0 + 0)));
      uint32_t m1 = rankof(mo | (1u << (p0 + 1)));
      uint32_t m2 = rankof(mo | (1u << (p0 + 2)));
      uint32_t m3 = rankof(mo | (1u << (p0 + 3)));
      uint32_t* pu = (uint32_t*)blk + (size_t)r * 4;
      pu[0] = m0 | (m1 << 16); pu[1] = m2 | (m3 << 16);
    } else if (r < PU_ROWS + W2_ROWS) {  // w=2 orbit: patterns 01,02,03,12,13,23
      int o = r - PU_ROWS;
      uint32_t mo = unrank_mask(12, 6, o, OUTPOS[b]);
      const uint32_t pat[6] = {0x3u, 0x5u, 0x9u, 0x6u, 0xAu, 0xCu};
      uint32_t k0 = rankof(mo | (pat[0] << p0)), k1 = rankof(mo | (pat[1] << p0));
      uint32_t k2 = rankof(mo | (pat[2] << p0)), k3 = rankof(mo | (pat[3] << p0));
      uint32_t k4 = rankof(mo | (pat[4] << p0)), k5 = rankof(mo | (pat[5] << p0));
      uint32_t* w2 = (uint32_t*)(blk + W2_SUB_OFF) + (size_t)o * 3;
      w2[0] = k0 | (k1 << 16); w2[1] = k2 | (k3 << 16); w2[2] = k4 | (k5 << 16);
    } else {                             // w=3 orbit: member m = hole at p0+m
      int o = r - PU_ROWS - W2_ROWS;
      uint32_t mo = unrank_mask(12, 5, o, OUTPOS[b]);
      uint32_t j0 = rankof(mo | (bmask ^ (1u << (p0 + 0))));
      uint32_t j1 = rankof(mo | (bmask ^ (1u << (p0 + 1))));
      uint32_t j2 = rankof(mo | (bmask ^ (1u << (p0 + 2))));
      uint32_t j3 = rankof(mo | (bmask ^ (1u << (p0 + 3))));
      uint32_t* pu = (uint32_t*)blk + (size_t)o * 4;
      pu[2] = j0 | (j1 << 16); pu[3] = j2 | (j3 << 16);
    }
  } else if (u < 13776) {                // boundary-orbit metadata
    int v = u - 10032;
    uint8_t* bnd = ws + BND_OFF;
    const uint32_t XL[3] = {1u << 3, 1u << 7, 1u << 11};
    const uint32_t XB[3] = {(1u<<3)|(1u<<4), (1u<<7)|(1u<<8), (1u<<11)|(1u<<12)};
    if (v < 252) {                       // m3: all three gates active
      uint32_t mo = unrank_mask(10, 5, v, FREEPOS);
      uint32_t rep = mo | XL[0] | XL[1] | XL[2];
      uint32_t mm[8];
      for (int beta = 0; beta < 8; ++beta) {
        uint32_t m = rep;
        if (beta & 1) m ^= XB[0];
        if (beta & 2) m ^= XB[1];
        if (beta & 4) m ^= XB[2];
        mm[beta] = rankof(m);
      }
      uint32_t* o = (uint32_t*)bnd + (size_t)v * 4;
      o[0] = mm[0] | (mm[1] << 16); o[1] = mm[2] | (mm[3] << 16);
      o[2] = mm[4] | (mm[5] << 16); o[3] = mm[6] | (mm[7] << 16);
    } else if (v < 1512) {               // m2: exactly two gates active
      int q = v - 252, cls = q / 420, o2 = q % 420;
      int gA = (cls == 2) ? 1 : 0;
      int gB = (cls == 0) ? 1 : 2;
      int gC = 3 - gA - gB;
      int vv = (o2 < 210) ? 0 : 1, oo = vv ? o2 - 210 : o2;
      uint32_t mo = unrank_mask(10, 6 - 2 * vv, oo, FREEPOS);
      uint32_t rep = mo | XL[gA] | XL[gB] | (vv ? XB[gC] : 0u);
      uint32_t mm[4];
      for (int beta = 0; beta < 4; ++beta) {
        uint32_t m = rep;
        if (beta & 1) m ^= XB[gA];
        if (beta & 2) m ^= XB[gB];
        mm[beta] = rankof(m);
      }
      uint32_t* o = (uint32_t*)(bnd + M2_OFF + (size_t)cls * 3360) + (size_t)o2 * 2;
      o[0] = mm[0] | (mm[1] << 16); o[1] = mm[2] | (mm[3] << 16);
    } else {                             // m1: one gate active
      int q = v - 1512, cls = q / 744, o2 = q % 744;
      int ia = (cls == 0) ? 1 : 0;
      int ib = (cls == 2) ? 1 : 2;
      int v1, v2, f, oo;
      if      (o2 < 120) { v1 = 0; v2 = 0; f = 7; oo = o2; }
      else if (o2 < 372) { v1 = 0; v2 = 1; f = 5; oo = o2 - 120; }
      else if (o2 < 624) { v1 = 1; v2 = 0; f = 5; oo = o2 - 372; }
      else               { v1 = 1; v2 = 1; f = 3; oo = o2 - 624; }
      uint32_t mo = unrank_mask(10, f, oo, FREEPOS);
      uint32_t rep = mo | XL[cls] | (v1 ? XB[ia] : 0u) | (v2 ? XB[ib] : 0u);
      uint32_t m0 = rankof(rep), m1 = rankof(rep ^ XB[cls]);
      *((uint32_t*)(bnd + M1_OFF + (size_t)cls * 2976) + o2) = m0 | (m1 << 16);
    }
  } else if (u < 14016) {                // cos/sin
    int g = u - 13776;
    float t = angles[g];
    ((float2*)(ws + CS_OFF))[g] = make_float2(cosf(t), sinf(t));
  }
}

// rot: a-role x gets c*x + s*y; b-role y gets c*y - s*x (matches reference).
__device__ __forceinline__ void rot(float& rx, float& ry, const float2 cs) {
  float nx = fmaf(cs.x, rx, cs.y * ry);
  float ny = fmaf(cs.x, ry, -cs.y * rx);
  rx = nx; ry = ny;
}

__global__ __launch_bounds__(TPB) void rbs_fused(
    const float* __restrict__ in, const uint8_t* __restrict__ ws,
    float* __restrict__ out) {
  __shared__ float st[NSTATES];
  __shared__ float2 csl[NGATES];
  const int tid = threadIdx.x;
  const size_t row = blockIdx.x;

  { const float2* s2 = (const float2*)(in + row * NSTATES);
    float2* l2 = (float2*)st;
    for (int i = tid; i < NSTATES / 2; i += TPB) l2[i] = s2[i]; }
  if (tid < NGATES) csl[tid] = ((const float2*)(ws + CS_OFF))[tid];
  __syncthreads();

  const uint8_t* blkbase = ws + BLK_OFF;
  const uint8_t* bnd = ws + BND_OFF;
  // static w2 assignment: threads <692 take id tid+232, threads 792..1023 take tid-792
  const int w2id = (tid < 692) ? (tid + 232) : ((tid >= 792) ? (tid - 792) : -1);

#pragma unroll 1
  for (int t = 0; t < NLP; ++t) {
    const int g0 = t * PERIOD;
#pragma unroll 1
    for (int b = 0; b < 4; ++b) {
      const float2 a1 = csl[g0 + 2 * b];       // (4b,4b+1)   even layer
      const float2 a2 = csl[g0 + 2 * b + 1];   // (4b+2,4b+3) even layer
      const float2 a3 = csl[g0 + 8 + 2 * b];   // (4b+1,4b+2) odd layer
      const uint8_t* blk = blkbase + b * BLK_BYTES;
      uint4 mu; uint32_t w0, w1, w2v;
      if (tid < PU_ROWS) mu = ((const uint4*)blk)[tid];
      if (w2id >= 0) {
        const uint32_t* p = (const uint32_t*)(blk + W2_SUB_OFF) + (size_t)w2id * 3;
        w0 = p[0]; w1 = p[1]; w2v = p[2];
      }
      if (tid < PU_ROWS) {
        // w=1: member m = occupied at inside pos m
        int i0 = mu.x & 0xffff, i1 = mu.x >> 16, i2 = mu.y & 0xffff, i3 = mu.y >> 16;
        float x0 = st[i0], x1 = st[i1], x2 = st[i2], x3 = st[i3];
        rot(x0, x1, a1); rot(x2, x3, a2); rot(x1, x2, a3);
        st[i0] = x0; st[i1] = x1; st[i2] = x2; st[i3] = x3;
        // w=3: member m = hole at inside pos m (roles swapped per gate)
        int j0 = mu.z & 0xffff, j1 = mu.z >> 16, j2 = mu.w & 0xffff, j3 = mu.w >> 16;
        float y0 = st[j0], y1 = st[j1], y2 = st[j2], y3 = st[j3];
        rot(y1, y0, a1); rot(y3, y2, a2); rot(y2, y1, a3);
        st[j0] = y0; st[j1] = y1; st[j2] = y2; st[j3] = y3;
      }
      if (w2id >= 0) {
        // patterns r0..r5 = 01,02,03,12,13,23 (occupied inside positions)
        int k0 = w0 & 0xffff, k1 = w0 >> 16, k2 = w1 & 0xffff, k3 = w1 >> 16;
        int k4 = w2v & 0xffff, k5 = w2v >> 16;
        float z0 = st[k0], z1 = st[k1], z2 = st[k2], z3 = st[k3], z4 = st[k4], z5 = st[k5];
        rot(z1, z3, a1); rot(z2, z4, a1);
        rot(z1, z2, a2); rot(z3, z4, a2);
        rot(z0, z1, a3); rot(z4, z5, a3);
        st[k0] = z0; st[k1] = z1; st[k2] = z2; st[k3] = z3; st[k4] = z4; st[k5] = z5;
      }
      __syncthreads();
    }
    // boundary gates (3,4),(7,8),(11,12) fused into orbits
    const float2 c0 = csl[g0 + 9], c1 = csl[g0 + 11], c2 = csl[g0 + 13];
#pragma unroll 1
    for (int u = tid; u < 3744; u += TPB) {
      if (u < 252) {
        const uint4 m = ((const uint4*)bnd)[u];
        int e0 = m.x & 0xffff, e1 = m.x >> 16, e2 = m.y & 0xffff, e3 = m.y >> 16;
        int e4 = m.z & 0xffff, e5 = m.z >> 16, e6 = m.w & 0xffff, e7 = m.w >> 16;
        float x0 = st[e0], x1 = st[e1], x2 = st[e2], x3 = st[e3];
        float x4 = st[e4], x5 = st[e5], x6 = st[e6], x7 = st[e7];
        rot(x0, x1, c0); rot(x2, x3, c0); rot(x4, x5, c0); rot(x6, x7, c0);
        rot(x0, x2, c1); rot(x1, x3, c1); rot(x4, x6, c1); rot(x5, x7, c1);
        rot(x0, x4, c2); rot(x1, x5, c2); rot(x2, x6, c2); rot(x3, x7, c2);
        st[e0] = x0; st[e1] = x1; st[e2] = x2; st[e3] = x3;
        st[e4] = x4; st[e5] = x5; st[e6] = x6; st[e7] = x7;
      } else if (u < 1512) {
        int q = u - 252, cls = q / 420, o = q % 420;
        float2 cA = (cls == 2) ? c1 : c0;
        float2 cB = (cls == 0) ? c1 : c2;
        const uint2 m = *(const uint2*)(bnd + M2_OFF + (size_t)cls * 3360 + (size_t)o * 8);
        int e0 = m.x & 0xffff, e1 = m.x >> 16, e2 = m.y & 0xffff, e3 = m.y >> 16;
        float x0 = st[e0], x1 = st[e1], x2 = st[e2], x3 = st[e3];
        rot(x0, x1, cA); rot(x2, x3, cA);
        rot(x0, x2, cB); rot(x1, x3, cB);
        st[e0] = x0; st[e1] = x1; st[e2] = x2; st[e3] = x3;
      } else {
        int q = u - 1512, cls = q / 744, o = q % 744;
        float2 cg = (cls == 0) ? c0 : ((cls == 1) ? c1 : c2);
        uint32_t m = *((const uint32_t*)(bnd + M1_OFF + (size_t)cls * 2976) + o);
        int e0 = m & 0xffff, e1 = m >> 16;
        float x0 = st[e0], x1 = st[e1];
        rot(x0, x1, cg);
        st[e0] = x0; st[e1] = x1;
      }
    }
    __syncthreads();
  }

  { float2* d2 = (float2*)(out + row * NSTATES);
    const float2* l2 = (const float2*)st;
    for (int i = tid; i < NSTATES / 2; i += TPB) d2[i] = l2[i]; }
}

// ---------------- fallback (no workspace): per-gate raw-pairs kernel ----------------
__global__ __launch_bounds__(TPB) void rbs_raw(
    const float* __restrict__ in, const int* __restrict__ pairs_raw,
    const float* __restrict__ angles, float* __restrict__ out) {
  __shared__ float st[NSTATES];
  __shared__ float2 csl[NGATES];
  const int tid = threadIdx.x;
  const size_t row = blockIdx.x;
  const float* src = in + row * NSTATES;
  for (int i = tid; i < NSTATES; i += TPB) st[i] = src[i];
  for (int i = tid; i < NGATES; i += TPB) {
    float t = angles[i];
    csl[i] = make_float2(cosf(t), sinf(t));
  }
  __syncthreads();
  for (int g = 0; g < NGATES; ++g) {
    const float c = csl[g].x, s = csl[g].y;
    for (int p = tid; p < NPAIRS; p += TPB) {
      int2 ab = ((const int2*)pairs_raw)[(size_t)g * NPAIRS + p];
      float xi = st[ab.x], xj = st[ab.y];
      st[ab.x] = fmaf(c, xi, s * xj);
      st[ab.y] = fmaf(c, xj, -s * xi);
    }
    __syncthreads();
  }
  float* dst = out + row * NSTATES;
  for (int i = tid; i < NSTATES; i += TPB) dst[i] = st[i];
}

extern "C" void kernel_launch(void* const* d_in, const int* in_sizes, int n_in,
                              void* d_out, int out_size, void* d_ws, size_t ws_size,
                              hipStream_t stream) {
  const float* in = (const float*)d_in[0];
  const float* angles = (const float*)d_in[1];
  const int* pairs = (const int*)d_in[2];
  float* out = (float*)d_out;

  if (d_ws != nullptr && ws_size >= WS_NEED) {
    uint8_t* ws = (uint8_t*)d_ws;
    prep_fused<<<55, 256, 0, stream>>>(angles, ws);
    rbs_fused<<<256, TPB, 0, stream>>>(in, ws, out);
  } else {
    rbs_raw<<<256, TPB, 0, stream>>>(in, pairs, angles, out);
  }
}